// Round 3
// 1233.469 us; speedup vs baseline: 1.1405x; 1.1405x over previous
//
#include <hip/hip_runtime.h>
#include <hip/hip_bf16.h>
#include <cstdint>
#include <cstddef>

#define N_NODES 100000
#define N_EDGES 3200000
#define D 256
#define SCAN_BLOCKS 391   // ceil(100000/256)

typedef __attribute__((ext_vector_type(8))) short short8;   // 8 bf16 = 4 VGPRs
typedef __attribute__((ext_vector_type(4))) float f32x4;

__device__ inline unsigned short f2bf(float f) {            // RNE fp32->bf16
    unsigned int u = __float_as_uint(f);
    u += 0x7FFFu + ((u >> 16) & 1u);
    return (unsigned short)(u >> 16);
}
__device__ inline float bf2f(unsigned short h) {
    return __uint_as_float(((unsigned int)h) << 16);
}

// ---------------------------------------------------------------------------
// CSR build: count -> scan -> fill    (edge_index arrives as int32!)
// ---------------------------------------------------------------------------
__global__ void count_kernel(const int* __restrict__ tgt, int* __restrict__ cnt) {
    int e = blockIdx.x * blockDim.x + threadIdx.x;
    if (e < N_EDGES) {
        int t = tgt[e];
        if (t >= 0 && t < N_NODES) atomicAdd(&cnt[t], 1);
    }
}

__global__ void scan1_kernel(const int* __restrict__ cnt, int* __restrict__ offs,
                             int* __restrict__ bsum) {
    __shared__ int s[256];
    int t = threadIdx.x;
    int i = blockIdx.x * 256 + t;
    int v = (i < N_NODES) ? cnt[i] : 0;
    s[t] = v;
    __syncthreads();
    for (int d = 1; d < 256; d <<= 1) {
        int x = (t >= d) ? s[t - d] : 0;
        __syncthreads();
        s[t] += x;
        __syncthreads();
    }
    if (i < N_NODES) offs[i + 1] = s[t];
    if (t == 255) bsum[blockIdx.x] = s[255];
}

__global__ void scan2_kernel(int* __restrict__ bsum) {
    __shared__ int s[512];
    int t = threadIdx.x;
    int v = (t < SCAN_BLOCKS) ? bsum[t] : 0;
    s[t] = v;
    __syncthreads();
    for (int d = 1; d < 512; d <<= 1) {
        int x = (t >= d) ? s[t - d] : 0;
        __syncthreads();
        s[t] += x;
        __syncthreads();
    }
    if (t < SCAN_BLOCKS) bsum[t] = (t == 0) ? 0 : s[t - 1];
}

__global__ void scan3_kernel(int* __restrict__ offs, const int* __restrict__ bsum) {
    int t = threadIdx.x;
    int i = blockIdx.x * 256 + t;
    if (i < N_NODES) offs[i + 1] += bsum[blockIdx.x];
    if (i == 0) offs[0] = 0;
}

__global__ void cursor_kernel(const int* __restrict__ offs, int* __restrict__ cursor) {
    int i = blockIdx.x * 256 + threadIdx.x;
    if (i < N_NODES) cursor[i] = offs[i];
}

__global__ void fill_kernel(const int* __restrict__ src,
                            const int* __restrict__ tgt,
                            int* __restrict__ cursor, int* __restrict__ sorted_src) {
    int e = blockIdx.x * blockDim.x + threadIdx.x;
    if (e < N_EDGES) {
        int t = tgt[e];
        int s = src[e];
        if (t >= 0 && t < N_NODES && s >= 0 && s < N_NODES) {
            int p = atomicAdd(&cursor[t], 1);
            sorted_src[p] = s;
        }
    }
}

// ---------------------------------------------------------------------------
// fp32 -> bf16 bulk convert (8 elements / thread)
// ---------------------------------------------------------------------------
__global__ __launch_bounds__(256) void convert_kernel(const float* __restrict__ in,
                                                      unsigned short* __restrict__ out,
                                                      int n8) {
    int i = blockIdx.x * 256 + threadIdx.x;
    if (i >= n8) return;
    const float4 a = ((const float4*)in)[i * 2 + 0];
    const float4 b = ((const float4*)in)[i * 2 + 1];
    short8 v;
    v[0] = (short)f2bf(a.x); v[1] = (short)f2bf(a.y);
    v[2] = (short)f2bf(a.z); v[3] = (short)f2bf(a.w);
    v[4] = (short)f2bf(b.x); v[5] = (short)f2bf(b.y);
    v[6] = (short)f2bf(b.z); v[7] = (short)f2bf(b.w);
    ((short8*)out)[i] = v;
}

// ---------------------------------------------------------------------------
// Pack B=[Wl;Wr] (512x256 fp32 row-major) into MFMA B-fragment order, bf16.
// Bp[((ntile*16 + kb)*64 + lane)*8 + j] = B[kb*32 + (lane>>4)*8 + j][ntile*16 + (lane&15)]
// ---------------------------------------------------------------------------
__global__ __launch_bounds__(256) void pack_b_kernel(const float* __restrict__ Wl,
                                                     const float* __restrict__ Wr,
                                                     unsigned short* __restrict__ Bp) {
    int t = blockIdx.x * 256 + threadIdx.x;   // 16*16*64 = 16384
    if (t >= 16384) return;
    int lane = t & 63, kb = (t >> 6) & 15, ntile = t >> 10;
    int n = ntile * 16 + (lane & 15);
    int kbase = kb * 32 + (lane >> 4) * 8;
    short8 v;
#pragma unroll
    for (int j = 0; j < 8; ++j) {
        int k = kbase + j;
        const float* W = (k < 256) ? Wl : Wr;
        v[j] = (short)f2bf(W[(size_t)(k & 255) * D + n]);
    }
    ((short8*)Bp)[t] = v;
}

// ---------------------------------------------------------------------------
// Mean aggregation over bf16 rows — MLP-optimized:
//   one wave per node; half-wave (32 lanes) per edge, 16 B (short8) per lane;
//   8 edges per iteration (4 gathers in flight); next iteration's indices
//   hand-pipelined so index-load latency is off the gather's address chain.
//   Cross-half combine via __shfl_xor(..,32); 32-lane coalesced 16 B store.
// ---------------------------------------------------------------------------
__device__ inline void acc8(float& a0, float& a1, float& a2, float& a3,
                            float& a4, float& a5, float& a6, float& a7,
                            const short8& r) {
    a0 += bf2f((unsigned short)r[0]); a1 += bf2f((unsigned short)r[1]);
    a2 += bf2f((unsigned short)r[2]); a3 += bf2f((unsigned short)r[3]);
    a4 += bf2f((unsigned short)r[4]); a5 += bf2f((unsigned short)r[5]);
    a6 += bf2f((unsigned short)r[6]); a7 += bf2f((unsigned short)r[7]);
}

__global__ __launch_bounds__(256) void aggregate_bf16(
    const unsigned short* __restrict__ in, unsigned short* __restrict__ out,
    const int* __restrict__ offs, const int* __restrict__ sorted_src) {
    int node = blockIdx.x * 4 + (threadIdx.x >> 6);
    if (node >= N_NODES) return;
    const int lane = threadIdx.x & 63;
    const int half = lane >> 5;                 // 0 or 1: which edge of a pair
    const int l32  = lane & 31;                 // 32 lanes x 8 bf16 = 256 cols
    const int beg = offs[node];
    const int deg = offs[node + 1] - beg;
    const unsigned short* __restrict__ rowp = in + (size_t)l32 * 8;

    float a0 = 0.f, a1 = 0.f, a2 = 0.f, a3 = 0.f;
    float a4 = 0.f, a5 = 0.f, a6 = 0.f, a7 = 0.f;

    // indices for iteration 0: edges (2*p + half), p = 0..3
    int i0 = (0 + half < deg) ? sorted_src[beg + 0 + half] : -1;
    int i1 = (2 + half < deg) ? sorted_src[beg + 2 + half] : -1;
    int i2 = (4 + half < deg) ? sorted_src[beg + 4 + half] : -1;
    int i3 = (6 + half < deg) ? sorted_src[beg + 6 + half] : -1;

    for (int k = 0; k < deg; k += 8) {
        // prefetch next iteration's indices (off the gather critical path)
        const int kn = k + 8;
        int n0 = (kn + 0 + half < deg) ? sorted_src[beg + kn + 0 + half] : -1;
        int n1 = (kn + 2 + half < deg) ? sorted_src[beg + kn + 2 + half] : -1;
        int n2 = (kn + 4 + half < deg) ? sorted_src[beg + kn + 4 + half] : -1;
        int n3 = (kn + 6 + half < deg) ? sorted_src[beg + kn + 6 + half] : -1;

        // 4 independent 16 B gathers per lane
        short8 r0 = {}, r1 = {}, r2 = {}, r3 = {};
        if (i0 >= 0) r0 = *(const short8*)(rowp + (size_t)i0 * D);
        if (i1 >= 0) r1 = *(const short8*)(rowp + (size_t)i1 * D);
        if (i2 >= 0) r2 = *(const short8*)(rowp + (size_t)i2 * D);
        if (i3 >= 0) r3 = *(const short8*)(rowp + (size_t)i3 * D);

        acc8(a0, a1, a2, a3, a4, a5, a6, a7, r0);
        acc8(a0, a1, a2, a3, a4, a5, a6, a7, r1);
        acc8(a0, a1, a2, a3, a4, a5, a6, a7, r2);
        acc8(a0, a1, a2, a3, a4, a5, a6, a7, r3);

        i0 = n0; i1 = n1; i2 = n2; i3 = n3;
    }

    // combine the two half-wave partial sums (once per node)
    a0 += __shfl_xor(a0, 32); a1 += __shfl_xor(a1, 32);
    a2 += __shfl_xor(a2, 32); a3 += __shfl_xor(a3, 32);
    a4 += __shfl_xor(a4, 32); a5 += __shfl_xor(a5, 32);
    a6 += __shfl_xor(a6, 32); a7 += __shfl_xor(a7, 32);

    if (half == 0) {
        const float inv = 1.0f / fmaxf((float)deg, 1.0f);
        short8 v;
        v[0] = (short)f2bf(a0 * inv); v[1] = (short)f2bf(a1 * inv);
        v[2] = (short)f2bf(a2 * inv); v[3] = (short)f2bf(a3 * inv);
        v[4] = (short)f2bf(a4 * inv); v[5] = (short)f2bf(a5 * inv);
        v[6] = (short)f2bf(a6 * inv); v[7] = (short)f2bf(a7 * inv);
        *(short8*)(out + (size_t)node * D + l32 * 8) = v;
    }
}

// ---------------------------------------------------------------------------
// MFMA GEMM: out = [A0 | A1] @ Bp + bias, K=512, optional ReLU, bf16/fp32 out.
// 256 thr = 4 waves; tile BM=128,BN=128,BK=32; each wave does 64x64 via 4x4
// of 16x16x32 MFMAs. A staged in LDS (padded); B fragments read straight from
// the packed 256 KB (L2-resident) buffer.
// ---------------------------------------------------------------------------
__global__ __launch_bounds__(256) void gemm_mfma(
    const unsigned short* __restrict__ A0, const unsigned short* __restrict__ A1,
    const unsigned short* __restrict__ Bp, const float* __restrict__ bias,
    void* __restrict__ outp, int relu, int out_bf16) {
    __shared__ unsigned short As[128][40];   // +8 pad: 80 B row stride
    const int m0 = blockIdx.y * 128;
    const int n0 = blockIdx.x * 128;
    const int t = threadIdx.x;
    const int wave = t >> 6, lane = t & 63;
    const int wy = wave >> 1, wx = wave & 1;
    const int quad = lane >> 4, l16 = lane & 15;

    const int arow = t >> 1;            // 0..127
    const int ahalf = (t & 1) * 16;     // 0 / 16 (bf16 elems)

    f32x4 acc[4][4] = {};

    for (int kb = 0; kb < 16; ++kb) {
        const int k0 = kb * 32;
        const unsigned short* A = (k0 < 256) ? A0 : A1;
        const int kk = k0 & 255;

        short8 v0 = {}, v1 = {};
        if (m0 + arow < N_NODES) {
            const unsigned short* p = A + (size_t)(m0 + arow) * D + kk + ahalf;
            v0 = *(const short8*)p;
            v1 = *(const short8*)(p + 8);
        }
        *(short8*)&As[arow][ahalf + 0] = v0;
        *(short8*)&As[arow][ahalf + 8] = v1;
        __syncthreads();

        short8 af[4], bf[4];
#pragma unroll
        for (int mi = 0; mi < 4; ++mi)
            af[mi] = *(const short8*)&As[wy * 64 + mi * 16 + l16][quad * 8];
#pragma unroll
        for (int ni = 0; ni < 4; ++ni) {
            int ntile = (n0 >> 4) + wx * 4 + ni;
            bf[ni] = ((const short8*)Bp)[(size_t)(ntile * 16 + kb) * 64 + lane];
        }
#pragma unroll
        for (int mi = 0; mi < 4; ++mi)
#pragma unroll
            for (int ni = 0; ni < 4; ++ni)
                acc[mi][ni] = __builtin_amdgcn_mfma_f32_16x16x32_bf16(
                    af[mi], bf[ni], acc[mi][ni], 0, 0, 0);
        __syncthreads();
    }

    unsigned short* ob = (unsigned short*)outp;
    float* of = (float*)outp;
#pragma unroll
    for (int ni = 0; ni < 4; ++ni) {
        const int col = n0 + wx * 64 + ni * 16 + l16;
        const float bcol = bias[col];
#pragma unroll
        for (int mi = 0; mi < 4; ++mi) {
#pragma unroll
            for (int r = 0; r < 4; ++r) {
                int row = m0 + wy * 64 + mi * 16 + quad * 4 + r;
                if (row < N_NODES) {
                    float v = acc[mi][ni][r] + bcol;
                    if (relu) v = fmaxf(v, 0.f);
                    if (out_bf16) ob[(size_t)row * D + col] = f2bf(v);
                    else          of[(size_t)row * D + col] = v;
                }
            }
        }
    }
}

// ---------------------------------------------------------------------------
extern "C" void kernel_launch(void* const* d_in, const int* in_sizes, int n_in,
                              void* d_out, int out_size, void* d_ws, size_t ws_size,
                              hipStream_t stream) {
    const float* x    = (const float*)d_in[0];
    const int*   ei   = (const int*)d_in[1];   // int32 on device!
    const float* W_l1 = (const float*)d_in[2];
    const float* b1   = (const float*)d_in[3];
    const float* W_r1 = (const float*)d_in[4];
    const float* W_l2 = (const float*)d_in[5];
    const float* b2   = (const float*)d_in[6];
    const float* W_r2 = (const float*)d_in[7];
    float* out = (float*)d_out;

    const int* src = ei;
    const int* tgt = ei + N_EDGES;

    char* w = (char*)d_ws;
    size_t o = 0;
    auto alloc = [&](size_t bytes) {
        size_t p = o;
        o = (o + bytes + 255) & ~(size_t)255;
        return p;
    };
    int* cnt        = (int*)(w + alloc((size_t)N_NODES * 4));
    int* offs       = (int*)(w + alloc((size_t)(N_NODES + 1) * 4));
    int* cursor     = (int*)(w + alloc((size_t)N_NODES * 4));
    int* bsum       = (int*)(w + alloc(512 * 4));
    int* sorted_src = (int*)(w + alloc((size_t)N_EDGES * 4));
    unsigned short* xb   = (unsigned short*)(w + alloc((size_t)N_NODES * D * 2));
    unsigned short* hb   = (unsigned short*)(w + alloc((size_t)N_NODES * D * 2));
    unsigned short* aggb = (unsigned short*)(w + alloc((size_t)N_NODES * D * 2));
    unsigned short* Bp1  = (unsigned short*)(w + alloc((size_t)512 * D * 2));
    unsigned short* Bp2  = (unsigned short*)(w + alloc((size_t)512 * D * 2));
    (void)ws_size; (void)in_sizes; (void)n_in; (void)out_size;

    hipMemsetAsync(cnt, 0, (size_t)N_NODES * 4, stream);

    const int EB = (N_EDGES + 255) / 256;
    count_kernel<<<EB, 256, 0, stream>>>(tgt, cnt);
    scan1_kernel<<<SCAN_BLOCKS, 256, 0, stream>>>(cnt, offs, bsum);
    scan2_kernel<<<1, 512, 0, stream>>>(bsum);
    scan3_kernel<<<SCAN_BLOCKS, 256, 0, stream>>>(offs, bsum);
    cursor_kernel<<<SCAN_BLOCKS, 256, 0, stream>>>(offs, cursor);
    fill_kernel<<<EB, 256, 0, stream>>>(src, tgt, cursor, sorted_src);

    // bf16 conversions / weight packing
    const int n8 = N_NODES * D / 8;            // 3.2M
    convert_kernel<<<(n8 + 255) / 256, 256, 0, stream>>>(x, xb, n8);
    pack_b_kernel<<<64, 256, 0, stream>>>(W_l1, W_r1, Bp1);
    pack_b_kernel<<<64, 256, 0, stream>>>(W_l2, W_r2, Bp2);

    const int AGG_B = (N_NODES + 3) / 4;
    dim3 ggrid(2, (N_NODES + 127) / 128);      // (2, 782)

    // Layer 1
    aggregate_bf16<<<AGG_B, 256, 0, stream>>>(xb, aggb, offs, sorted_src);
    gemm_mfma<<<ggrid, 256, 0, stream>>>(aggb, xb, Bp1, b1, hb, 1, 1);

    // Layer 2
    aggregate_bf16<<<AGG_B, 256, 0, stream>>>(hb, aggb, offs, sorted_src);
    gemm_mfma<<<ggrid, 256, 0, stream>>>(aggb, hb, Bp2, b2, out, 0, 0);
}

// Round 5
// 1076.816 us; speedup vs baseline: 1.3064x; 1.1455x over previous
//
#include <hip/hip_runtime.h>
#include <hip/hip_bf16.h>
#include <cstdint>
#include <cstddef>

#define N_NODES 100000
#define N_EDGES 3200000
#define D 256
#define CAP 64            // per-node inline bucket capacity (deg ~ Poisson(32))
#define OVF_MAX (1 << 20) // overflow list capacity (guaranteed-correct fallback)

typedef __attribute__((ext_vector_type(8))) short short8;   // 8 bf16 = 4 VGPRs
typedef __attribute__((ext_vector_type(4))) float f32x4;

__device__ inline unsigned short f2bf(float f) {            // RNE fp32->bf16
    unsigned int u = __float_as_uint(f);
    u += 0x7FFFu + ((u >> 16) & 1u);
    return (unsigned short)(u >> 16);
}
__device__ inline float bf2f(unsigned short h) {
    return __uint_as_float(((unsigned int)h) << 16);
}

// ---------------------------------------------------------------------------
// Single-pass bucket fill: ONE random-atomic pass (vs count+scan+fill's two).
// p = rank of edge within its target node; in-bucket if p < CAP, else the
// (t,s) pair goes to a global overflow list handled by the aggregate.
// ---------------------------------------------------------------------------
__global__ void fill_bucket(const int* __restrict__ src,
                            const int* __restrict__ tgt,
                            int* __restrict__ cnt,
                            int* __restrict__ bucket,
                            int2* __restrict__ ovf,
                            int* __restrict__ ovf_cnt) {
    int e = blockIdx.x * blockDim.x + threadIdx.x;
    if (e >= N_EDGES) return;
    int t = tgt[e];
    int s = src[e];
    if (t >= 0 && t < N_NODES && s >= 0 && s < N_NODES) {
        int p = atomicAdd(&cnt[t], 1);
        if (p < CAP) {
            bucket[(size_t)t * CAP + p] = s;
        } else {
            int q = atomicAdd(ovf_cnt, 1);
            if (q < OVF_MAX) ovf[q] = make_int2(t, s);
        }
    }
}

// ---------------------------------------------------------------------------
// fp32 -> bf16 bulk convert (8 elements / thread)
// ---------------------------------------------------------------------------
__global__ __launch_bounds__(256) void convert_kernel(const float* __restrict__ in,
                                                      unsigned short* __restrict__ out,
                                                      int n8) {
    int i = blockIdx.x * 256 + threadIdx.x;
    if (i >= n8) return;
    const float4 a = ((const float4*)in)[i * 2 + 0];
    const float4 b = ((const float4*)in)[i * 2 + 1];
    short8 v;
    v[0] = (short)f2bf(a.x); v[1] = (short)f2bf(a.y);
    v[2] = (short)f2bf(a.z); v[3] = (short)f2bf(a.w);
    v[4] = (short)f2bf(b.x); v[5] = (short)f2bf(b.y);
    v[6] = (short)f2bf(b.z); v[7] = (short)f2bf(b.w);
    ((short8*)out)[i] = v;
}

// ---------------------------------------------------------------------------
// Pack B=[Wl;Wr] (512x256 fp32 row-major) into MFMA B-fragment order, bf16.
// Bp[((ntile*16 + kb)*64 + lane)*8 + j] = B[kb*32 + (lane>>4)*8 + j][ntile*16 + (lane&15)]
// ---------------------------------------------------------------------------
__global__ __launch_bounds__(256) void pack_b_kernel(const float* __restrict__ Wl,
                                                     const float* __restrict__ Wr,
                                                     unsigned short* __restrict__ Bp) {
    int t = blockIdx.x * 256 + threadIdx.x;   // 16*16*64 = 16384
    if (t >= 16384) return;
    int lane = t & 63, kb = (t >> 6) & 15, ntile = t >> 10;
    int n = ntile * 16 + (lane & 15);
    int kbase = kb * 32 + (lane >> 4) * 8;
    short8 v;
#pragma unroll
    for (int j = 0; j < 8; ++j) {
        int k = kbase + j;
        const float* W = (k < 256) ? Wl : Wr;
        v[j] = (short)f2bf(W[(size_t)(k & 255) * D + n]);
    }
    ((short8*)Bp)[t] = v;
}

// ---------------------------------------------------------------------------
// Mean aggregation over bf16 rows — MLP-optimized (one wave per node):
//   half-wave (32 lanes) per edge, 16 B (short8) per lane; 8 edges per
//   iteration (4 gathers in flight); next iteration's indices pipelined.
//   Sources come from the fixed-capacity bucket; deg>CAP falls back to a
//   scan of the (normally empty) overflow list. Mean uses the TRUE degree.
// ---------------------------------------------------------------------------
__device__ inline void acc8(float& a0, float& a1, float& a2, float& a3,
                            float& a4, float& a5, float& a6, float& a7,
                            const short8& r) {
    a0 += bf2f((unsigned short)r[0]); a1 += bf2f((unsigned short)r[1]);
    a2 += bf2f((unsigned short)r[2]); a3 += bf2f((unsigned short)r[3]);
    a4 += bf2f((unsigned short)r[4]); a5 += bf2f((unsigned short)r[5]);
    a6 += bf2f((unsigned short)r[6]); a7 += bf2f((unsigned short)r[7]);
}

__global__ __launch_bounds__(256) void aggregate_bf16(
    const unsigned short* __restrict__ in, unsigned short* __restrict__ out,
    const int* __restrict__ cnt, const int* __restrict__ bucket,
    const int2* __restrict__ ovf, const int* __restrict__ ovf_cnt) {
    int node = blockIdx.x * 4 + (threadIdx.x >> 6);
    if (node >= N_NODES) return;
    const int lane = threadIdx.x & 63;
    const int half = lane >> 5;                 // 0 or 1: which edge of a pair
    const int l32  = lane & 31;                 // 32 lanes x 8 bf16 = 256 cols
    const int deg = cnt[node];
    const int inb = (deg < CAP) ? deg : CAP;    // entries present in bucket
    const int* __restrict__ bk = bucket + (size_t)node * CAP;
    const unsigned short* __restrict__ rowp = in + (size_t)l32 * 8;

    float a0 = 0.f, a1 = 0.f, a2 = 0.f, a3 = 0.f;
    float a4 = 0.f, a5 = 0.f, a6 = 0.f, a7 = 0.f;

    // indices for iteration 0: edges (2*p + half), p = 0..3
    int i0 = (0 + half < inb) ? bk[0 + half] : -1;
    int i1 = (2 + half < inb) ? bk[2 + half] : -1;
    int i2 = (4 + half < inb) ? bk[4 + half] : -1;
    int i3 = (6 + half < inb) ? bk[6 + half] : -1;

    for (int k = 0; k < inb; k += 8) {
        // prefetch next iteration's indices (off the gather critical path)
        const int kn = k + 8;
        int n0 = (kn + 0 + half < inb) ? bk[kn + 0 + half] : -1;
        int n1 = (kn + 2 + half < inb) ? bk[kn + 2 + half] : -1;
        int n2 = (kn + 4 + half < inb) ? bk[kn + 4 + half] : -1;
        int n3 = (kn + 6 + half < inb) ? bk[kn + 6 + half] : -1;

        // 4 independent 16 B gathers per lane
        short8 r0 = {}, r1 = {}, r2 = {}, r3 = {};
        if (i0 >= 0) r0 = *(const short8*)(rowp + (size_t)i0 * D);
        if (i1 >= 0) r1 = *(const short8*)(rowp + (size_t)i1 * D);
        if (i2 >= 0) r2 = *(const short8*)(rowp + (size_t)i2 * D);
        if (i3 >= 0) r3 = *(const short8*)(rowp + (size_t)i3 * D);

        acc8(a0, a1, a2, a3, a4, a5, a6, a7, r0);
        acc8(a0, a1, a2, a3, a4, a5, a6, a7, r1);
        acc8(a0, a1, a2, a3, a4, a5, a6, a7, r2);
        acc8(a0, a1, a2, a3, a4, a5, a6, a7, r3);

        i0 = n0; i1 = n1; i2 = n2; i3 = n3;
    }

    // rare path: this node overflowed the bucket -> scan the overflow list
    if (deg > CAP) {
        int m = *ovf_cnt;
        if (m > OVF_MAX) m = OVF_MAX;
        for (int q = half; q < m; q += 2) {
            int2 ts = ovf[q];
            if (ts.x == node) {
                short8 r = *(const short8*)(rowp + (size_t)ts.y * D);
                acc8(a0, a1, a2, a3, a4, a5, a6, a7, r);
            }
        }
    }

    // combine the two half-wave partial sums (once per node)
    a0 += __shfl_xor(a0, 32); a1 += __shfl_xor(a1, 32);
    a2 += __shfl_xor(a2, 32); a3 += __shfl_xor(a3, 32);
    a4 += __shfl_xor(a4, 32); a5 += __shfl_xor(a5, 32);
    a6 += __shfl_xor(a6, 32); a7 += __shfl_xor(a7, 32);

    if (half == 0) {
        const float inv = 1.0f / fmaxf((float)deg, 1.0f);
        short8 v;
        v[0] = (short)f2bf(a0 * inv); v[1] = (short)f2bf(a1 * inv);
        v[2] = (short)f2bf(a2 * inv); v[3] = (short)f2bf(a3 * inv);
        v[4] = (short)f2bf(a4 * inv); v[5] = (short)f2bf(a5 * inv);
        v[6] = (short)f2bf(a6 * inv); v[7] = (short)f2bf(a7 * inv);
        *(short8*)(out + (size_t)node * D + l32 * 8) = v;
    }
}

// ---------------------------------------------------------------------------
// MFMA GEMM: out = [A0 | A1] @ Bp + bias, K=512, optional ReLU, bf16/fp32 out.
// 256 thr = 4 waves; tile BM=128,BN=128,BK=32; each wave does 64x64 via 4x4
// of 16x16x32 MFMAs. A staged in LDS (padded); B fragments read straight from
// the packed 256 KB (L2-resident) buffer.
// ---------------------------------------------------------------------------
__global__ __launch_bounds__(256) void gemm_mfma(
    const unsigned short* __restrict__ A0, const unsigned short* __restrict__ A1,
    const unsigned short* __restrict__ Bp, const float* __restrict__ bias,
    void* __restrict__ outp, int relu, int out_bf16) {
    __shared__ unsigned short As[128][40];   // +8 pad: 80 B row stride
    const int m0 = blockIdx.y * 128;
    const int n0 = blockIdx.x * 128;
    const int t = threadIdx.x;
    const int wave = t >> 6, lane = t & 63;
    const int wy = wave >> 1, wx = wave & 1;
    const int quad = lane >> 4, l16 = lane & 15;

    const int arow = t >> 1;            // 0..127
    const int ahalf = (t & 1) * 16;     // 0 / 16 (bf16 elems)

    f32x4 acc[4][4] = {};

    for (int kb = 0; kb < 16; ++kb) {
        const int k0 = kb * 32;
        const unsigned short* A = (k0 < 256) ? A0 : A1;
        const int kk = k0 & 255;

        short8 v0 = {}, v1 = {};
        if (m0 + arow < N_NODES) {
            const unsigned short* p = A + (size_t)(m0 + arow) * D + kk + ahalf;
            v0 = *(const short8*)p;
            v1 = *(const short8*)(p + 8);
        }
        *(short8*)&As[arow][ahalf + 0] = v0;
        *(short8*)&As[arow][ahalf + 8] = v1;
        __syncthreads();

        short8 af[4], bf[4];
#pragma unroll
        for (int mi = 0; mi < 4; ++mi)
            af[mi] = *(const short8*)&As[wy * 64 + mi * 16 + l16][quad * 8];
#pragma unroll
        for (int ni = 0; ni < 4; ++ni) {
            int ntile = (n0 >> 4) + wx * 4 + ni;
            bf[ni] = ((const short8*)Bp)[(size_t)(ntile * 16 + kb) * 64 + lane];
        }
#pragma unroll
        for (int mi = 0; mi < 4; ++mi)
#pragma unroll
            for (int ni = 0; ni < 4; ++ni)
                acc[mi][ni] = __builtin_amdgcn_mfma_f32_16x16x32_bf16(
                    af[mi], bf[ni], acc[mi][ni], 0, 0, 0);
        __syncthreads();
    }

    unsigned short* ob = (unsigned short*)outp;
    float* of = (float*)outp;
#pragma unroll
    for (int ni = 0; ni < 4; ++ni) {
        const int col = n0 + wx * 64 + ni * 16 + l16;
        const float bcol = bias[col];
#pragma unroll
        for (int mi = 0; mi < 4; ++mi) {
#pragma unroll
            for (int r = 0; r < 4; ++r) {
                int row = m0 + wy * 64 + mi * 16 + quad * 4 + r;
                if (row < N_NODES) {
                    float v = acc[mi][ni][r] + bcol;
                    if (relu) v = fmaxf(v, 0.f);
                    if (out_bf16) ob[(size_t)row * D + col] = f2bf(v);
                    else          of[(size_t)row * D + col] = v;
                }
            }
        }
    }
}

// ---------------------------------------------------------------------------
extern "C" void kernel_launch(void* const* d_in, const int* in_sizes, int n_in,
                              void* d_out, int out_size, void* d_ws, size_t ws_size,
                              hipStream_t stream) {
    const float* x    = (const float*)d_in[0];
    const int*   ei   = (const int*)d_in[1];   // int32 on device!
    const float* W_l1 = (const float*)d_in[2];
    const float* b1   = (const float*)d_in[3];
    const float* W_r1 = (const float*)d_in[4];
    const float* W_l2 = (const float*)d_in[5];
    const float* b2   = (const float*)d_in[6];
    const float* W_r2 = (const float*)d_in[7];
    float* out = (float*)d_out;

    const int* src = ei;
    const int* tgt = ei + N_EDGES;

    char* w = (char*)d_ws;
    size_t o = 0;
    auto alloc = [&](size_t bytes) {
        size_t p = o;
        o = (o + bytes + 255) & ~(size_t)255;
        return p;
    };
    int*  cnt     = (int*)(w + alloc((size_t)N_NODES * 4));
    int*  ovf_cnt = (int*)(w + alloc(256));
    int*  bucket  = (int*)(w + alloc((size_t)N_NODES * CAP * 4));
    int2* ovf     = (int2*)(w + alloc((size_t)OVF_MAX * 8));
    unsigned short* xb   = (unsigned short*)(w + alloc((size_t)N_NODES * D * 2));
    unsigned short* hb   = (unsigned short*)(w + alloc((size_t)N_NODES * D * 2));
    unsigned short* aggb = (unsigned short*)(w + alloc((size_t)N_NODES * D * 2));
    unsigned short* Bp1  = (unsigned short*)(w + alloc((size_t)512 * D * 2));
    unsigned short* Bp2  = (unsigned short*)(w + alloc((size_t)512 * D * 2));
    (void)ws_size; (void)in_sizes; (void)n_in; (void)out_size;

    hipMemsetAsync(cnt, 0, (size_t)N_NODES * 4, stream);
    hipMemsetAsync(ovf_cnt, 0, 4, stream);

    const int EB = (N_EDGES + 255) / 256;
    fill_bucket<<<EB, 256, 0, stream>>>(src, tgt, cnt, bucket, ovf, ovf_cnt);

    // bf16 conversions / weight packing
    const int n8 = N_NODES * D / 8;            // 3.2M
    convert_kernel<<<(n8 + 255) / 256, 256, 0, stream>>>(x, xb, n8);
    pack_b_kernel<<<64, 256, 0, stream>>>(W_l1, W_r1, Bp1);
    pack_b_kernel<<<64, 256, 0, stream>>>(W_l2, W_r2, Bp2);

    const int AGG_B = (N_NODES + 3) / 4;
    dim3 ggrid(2, (N_NODES + 127) / 128);      // (2, 782)

    // Layer 1
    aggregate_bf16<<<AGG_B, 256, 0, stream>>>(xb, aggb, cnt, bucket, ovf, ovf_cnt);
    gemm_mfma<<<ggrid, 256, 0, stream>>>(aggb, xb, Bp1, b1, hb, 1, 1);

    // Layer 2
    aggregate_bf16<<<AGG_B, 256, 0, stream>>>(hb, aggb, cnt, bucket, ovf, ovf_cnt);
    gemm_mfma<<<ggrid, 256, 0, stream>>>(aggb, hb, Bp2, b2, out, 0, 0);
}

// Round 7
// 1062.581 us; speedup vs baseline: 1.3239x; 1.0134x over previous
//
#include <hip/hip_runtime.h>
#include <hip/hip_bf16.h>
#include <cstdint>
#include <cstddef>

#define N_NODES 100000
#define N_EDGES 3200000
#define D 256
#define NBINS 1563          // ceil(100000/64), bin = tgt >> 6
#define CAPB 2560           // per-bin capacity: mean 2048, +11 sigma
#define CNT_STRIDE 16       // pad bin counters to 64 B (kill same-line atomic serialization)
#define OVF_MAX (1 << 20)   // overflow list capacity (guaranteed-correct fallback)

typedef __attribute__((ext_vector_type(8))) short short8;   // 8 bf16 = 4 VGPRs
typedef __attribute__((ext_vector_type(4))) float f32x4;

__device__ inline unsigned short f2bf(float f) {            // RNE fp32->bf16
    unsigned int u = __float_as_uint(f);
    u += 0x7FFFu + ((u >> 16) & 1u);
    return (unsigned short)(u >> 16);
}
__device__ inline float bf2f(unsigned short h) {
    return __uint_as_float(((unsigned int)h) << 16);
}

// ---------------------------------------------------------------------------
// Pass 1: bin-append. Concurrent appends to a bin land at consecutive ranks
// -> same 64B lines -> L2 write-combining (vs 15x line amplification of the
// node-random scatter). Entry packs (t_local<<17 | s) into 4 B (s < 2^17).
// ---------------------------------------------------------------------------
__global__ void binfill_kernel(const int* __restrict__ src,
                               const int* __restrict__ tgt,
                               int* __restrict__ bin_cnt,
                               unsigned int* __restrict__ bin_buf,
                               int2* __restrict__ ovf,
                               int* __restrict__ ovf_cnt) {
    int e = blockIdx.x * blockDim.x + threadIdx.x;
    if (e >= N_EDGES) return;
    int t = tgt[e];
    int s = src[e];
    if (t >= 0 && t < N_NODES && s >= 0 && s < N_NODES) {
        int b = t >> 6;
        int p = atomicAdd(&bin_cnt[b * CNT_STRIDE], 1);
        if (p < CAPB) {
            bin_buf[(size_t)b * CAPB + p] = ((unsigned int)(t & 63) << 17) | (unsigned int)s;
        } else {
            int q = atomicAdd(ovf_cnt, 1);
            if (q < OVF_MAX) ovf[q] = make_int2(t, s);
        }
    }
}

// ---------------------------------------------------------------------------
// Exclusive scan over the 1563 bin counts (clamped to CAPB) -> bin_base.
// Single block, 7 chunks of 256. Also writes offs[N_NODES] = total.
// ---------------------------------------------------------------------------
__global__ __launch_bounds__(256) void scan_bins(const int* __restrict__ bin_cnt,
                                                 int* __restrict__ bin_base,
                                                 int* __restrict__ offs) {
    __shared__ int s[256];
    __shared__ int carry;
    const int t = threadIdx.x;
    if (t == 0) carry = 0;
    __syncthreads();
    for (int chunk = 0; chunk < (NBINS + 255) / 256; ++chunk) {
        int b = chunk * 256 + t;
        int v = 0;
        if (b < NBINS) {
            v = bin_cnt[b * CNT_STRIDE];
            if (v > CAPB) v = CAPB;
        }
        s[t] = v;
        __syncthreads();
        for (int d = 1; d < 256; d <<= 1) {
            int x = (t >= d) ? s[t - d] : 0;
            __syncthreads();
            s[t] += x;
            __syncthreads();
        }
        if (b < NBINS) bin_base[b] = carry + s[t] - v;   // exclusive
        __syncthreads();
        if (t == 0) carry += s[255];
        __syncthreads();
    }
    if (t == 0) {
        bin_base[NBINS] = carry;
        offs[N_NODES] = carry;
    }
}

// ---------------------------------------------------------------------------
// Pass 2: per-bin expansion into a dense exact CSR. One block per bin.
// Entries staged in LDS; per-node counts/offsets via LDS atomics (no global
// atomics); coalesced bin reads, bin-local (line-friendly) CSR writes.
// ---------------------------------------------------------------------------
__global__ __launch_bounds__(256) void bin_expand(const int* __restrict__ bin_cnt,
                                                  const int* __restrict__ bin_base,
                                                  const unsigned int* __restrict__ bin_buf,
                                                  int* __restrict__ offs,
                                                  int* __restrict__ sorted_src) {
    __shared__ unsigned int ent[CAPB];
    __shared__ int cnt64[64], off64[64], cur64[64];
    const int b = blockIdx.x;
    const int tid = threadIdx.x;
    int n = bin_cnt[b * CNT_STRIDE];
    if (n > CAPB) n = CAPB;
    const int base = bin_base[b];

    if (tid < 64) cnt64[tid] = 0;
    __syncthreads();
    for (int i = tid; i < n; i += 256) {
        unsigned int v = bin_buf[(size_t)b * CAPB + i];
        ent[i] = v;
        atomicAdd(&cnt64[v >> 17], 1);
    }
    __syncthreads();
    if (tid == 0) {
        int run = 0;
#pragma unroll
        for (int i = 0; i < 64; ++i) { off64[i] = run; run += cnt64[i]; }
    }
    __syncthreads();
    if (tid < 64) {
        cur64[tid] = off64[tid];
        int node = b * 64 + tid;
        if (node < N_NODES) offs[node] = base + off64[tid];
    }
    __syncthreads();
    for (int i = tid; i < n; i += 256) {
        unsigned int v = ent[i];
        int p = atomicAdd(&cur64[v >> 17], 1);
        sorted_src[base + p] = (int)(v & 0x1FFFFu);
    }
}

// ---------------------------------------------------------------------------
// fp32 -> bf16 bulk convert (8 elements / thread)
// ---------------------------------------------------------------------------
__global__ __launch_bounds__(256) void convert_kernel(const float* __restrict__ in,
                                                      unsigned short* __restrict__ out,
                                                      int n8) {
    int i = blockIdx.x * 256 + threadIdx.x;
    if (i >= n8) return;
    const float4 a = ((const float4*)in)[i * 2 + 0];
    const float4 b = ((const float4*)in)[i * 2 + 1];
    short8 v;
    v[0] = (short)f2bf(a.x); v[1] = (short)f2bf(a.y);
    v[2] = (short)f2bf(a.z); v[3] = (short)f2bf(a.w);
    v[4] = (short)f2bf(b.x); v[5] = (short)f2bf(b.y);
    v[6] = (short)f2bf(b.z); v[7] = (short)f2bf(b.w);
    ((short8*)out)[i] = v;
}

// ---------------------------------------------------------------------------
// Pack B=[Wl;Wr] (512x256 fp32 row-major) into MFMA B-fragment order, bf16.
// ---------------------------------------------------------------------------
__global__ __launch_bounds__(256) void pack_b_kernel(const float* __restrict__ Wl,
                                                     const float* __restrict__ Wr,
                                                     unsigned short* __restrict__ Bp) {
    int t = blockIdx.x * 256 + threadIdx.x;   // 16*16*64 = 16384
    if (t >= 16384) return;
    int lane = t & 63, kb = (t >> 6) & 15, ntile = t >> 10;
    int n = ntile * 16 + (lane & 15);
    int kbase = kb * 32 + (lane >> 4) * 8;
    short8 v;
#pragma unroll
    for (int j = 0; j < 8; ++j) {
        int k = kbase + j;
        const float* W = (k < 256) ? Wl : Wr;
        v[j] = (short)f2bf(W[(size_t)(k & 255) * D + n]);
    }
    ((short8*)Bp)[t] = v;
}

// ---------------------------------------------------------------------------
// Mean aggregation over bf16 rows (one wave per node, CSR):
//   half-wave per edge, 16 B short8 per lane; 8 edges/iter (4 gathers in
//   flight); next iteration's indices pipelined. Overflow list (normally
//   empty) scanned only when non-empty; mean divisor uses the exact degree.
// ---------------------------------------------------------------------------
__device__ inline void acc8(float& a0, float& a1, float& a2, float& a3,
                            float& a4, float& a5, float& a6, float& a7,
                            const short8& r) {
    a0 += bf2f((unsigned short)r[0]); a1 += bf2f((unsigned short)r[1]);
    a2 += bf2f((unsigned short)r[2]); a3 += bf2f((unsigned short)r[3]);
    a4 += bf2f((unsigned short)r[4]); a5 += bf2f((unsigned short)r[5]);
    a6 += bf2f((unsigned short)r[6]); a7 += bf2f((unsigned short)r[7]);
}

__global__ __launch_bounds__(256) void aggregate_bf16(
    const unsigned short* __restrict__ in, unsigned short* __restrict__ out,
    const int* __restrict__ offs, const int* __restrict__ sorted_src,
    const int2* __restrict__ ovf, const int* __restrict__ ovf_cnt) {
    int node = blockIdx.x * 4 + (threadIdx.x >> 6);
    if (node >= N_NODES) return;
    const int lane = threadIdx.x & 63;
    const int half = lane >> 5;                 // 0 or 1: which edge of a pair
    const int l32  = lane & 31;                 // 32 lanes x 8 bf16 = 256 cols
    const int beg = offs[node];
    const int inb = offs[node + 1] - beg;
    const unsigned short* __restrict__ rowp = in + (size_t)l32 * 8;

    float a0 = 0.f, a1 = 0.f, a2 = 0.f, a3 = 0.f;
    float a4 = 0.f, a5 = 0.f, a6 = 0.f, a7 = 0.f;

    // indices for iteration 0: edges (2*p + half), p = 0..3
    int i0 = (0 + half < inb) ? sorted_src[beg + 0 + half] : -1;
    int i1 = (2 + half < inb) ? sorted_src[beg + 2 + half] : -1;
    int i2 = (4 + half < inb) ? sorted_src[beg + 4 + half] : -1;
    int i3 = (6 + half < inb) ? sorted_src[beg + 6 + half] : -1;

    for (int k = 0; k < inb; k += 8) {
        // prefetch next iteration's indices (off the gather critical path)
        const int kn = k + 8;
        int n0 = (kn + 0 + half < inb) ? sorted_src[beg + kn + 0 + half] : -1;
        int n1 = (kn + 2 + half < inb) ? sorted_src[beg + kn + 2 + half] : -1;
        int n2 = (kn + 4 + half < inb) ? sorted_src[beg + kn + 4 + half] : -1;
        int n3 = (kn + 6 + half < inb) ? sorted_src[beg + kn + 6 + half] : -1;

        // 4 independent 16 B gathers per lane
        short8 r0 = {}, r1 = {}, r2 = {}, r3 = {};
        if (i0 >= 0) r0 = *(const short8*)(rowp + (size_t)i0 * D);
        if (i1 >= 0) r1 = *(const short8*)(rowp + (size_t)i1 * D);
        if (i2 >= 0) r2 = *(const short8*)(rowp + (size_t)i2 * D);
        if (i3 >= 0) r3 = *(const short8*)(rowp + (size_t)i3 * D);

        acc8(a0, a1, a2, a3, a4, a5, a6, a7, r0);
        acc8(a0, a1, a2, a3, a4, a5, a6, a7, r1);
        acc8(a0, a1, a2, a3, a4, a5, a6, a7, r2);
        acc8(a0, a1, a2, a3, a4, a5, a6, a7, r3);

        i0 = n0; i1 = n1; i2 = n2; i3 = n3;
    }

    // rare path: some bin overflowed -> scan the (tiny) overflow list
    int extra = 0;
    int m = *ovf_cnt;
    if (m > 0) {
        if (m > OVF_MAX) m = OVF_MAX;
        for (int q = half; q < m; q += 2) {
            int2 ts = ovf[q];
            if (ts.x == node) {
                short8 r = *(const short8*)(rowp + (size_t)ts.y * D);
                acc8(a0, a1, a2, a3, a4, a5, a6, a7, r);
                ++extra;
            }
        }
    }

    // combine the two half-wave partial sums (once per node)
    a0 += __shfl_xor(a0, 32); a1 += __shfl_xor(a1, 32);
    a2 += __shfl_xor(a2, 32); a3 += __shfl_xor(a3, 32);
    a4 += __shfl_xor(a4, 32); a5 += __shfl_xor(a5, 32);
    a6 += __shfl_xor(a6, 32); a7 += __shfl_xor(a7, 32);
    extra += __shfl_xor(extra, 32);

    if (half == 0) {
        const float inv = 1.0f / fmaxf((float)(inb + extra), 1.0f);
        short8 v;
        v[0] = (short)f2bf(a0 * inv); v[1] = (short)f2bf(a1 * inv);
        v[2] = (short)f2bf(a2 * inv); v[3] = (short)f2bf(a3 * inv);
        v[4] = (short)f2bf(a4 * inv); v[5] = (short)f2bf(a5 * inv);
        v[6] = (short)f2bf(a6 * inv); v[7] = (short)f2bf(a7 * inv);
        *(short8*)(out + (size_t)node * D + l32 * 8) = v;
    }
}

// ---------------------------------------------------------------------------
// MFMA GEMM: out = [A0 | A1] @ Bp + bias, K=512, optional ReLU, bf16/fp32 out.
// ---------------------------------------------------------------------------
__global__ __launch_bounds__(256) void gemm_mfma(
    const unsigned short* __restrict__ A0, const unsigned short* __restrict__ A1,
    const unsigned short* __restrict__ Bp, const float* __restrict__ bias,
    void* __restrict__ outp, int relu, int out_bf16) {
    __shared__ unsigned short As[128][40];   // +8 pad: 80 B row stride
    const int m0 = blockIdx.y * 128;
    const int n0 = blockIdx.x * 128;
    const int t = threadIdx.x;
    const int wave = t >> 6, lane = t & 63;
    const int wy = wave >> 1, wx = wave & 1;
    const int quad = lane >> 4, l16 = lane & 15;

    const int arow = t >> 1;            // 0..127
    const int ahalf = (t & 1) * 16;     // 0 / 16 (bf16 elems)

    f32x4 acc[4][4] = {};

    for (int kb = 0; kb < 16; ++kb) {
        const int k0 = kb * 32;
        const unsigned short* A = (k0 < 256) ? A0 : A1;
        const int kk = k0 & 255;

        short8 v0 = {}, v1 = {};
        if (m0 + arow < N_NODES) {
            const unsigned short* p = A + (size_t)(m0 + arow) * D + kk + ahalf;
            v0 = *(const short8*)p;
            v1 = *(const short8*)(p + 8);
        }
        *(short8*)&As[arow][ahalf + 0] = v0;
        *(short8*)&As[arow][ahalf + 8] = v1;
        __syncthreads();

        short8 af[4], bf[4];
#pragma unroll
        for (int mi = 0; mi < 4; ++mi)
            af[mi] = *(const short8*)&As[wy * 64 + mi * 16 + l16][quad * 8];
#pragma unroll
        for (int ni = 0; ni < 4; ++ni) {
            int ntile = (n0 >> 4) + wx * 4 + ni;
            bf[ni] = ((const short8*)Bp)[(size_t)(ntile * 16 + kb) * 64 + lane];
        }
#pragma unroll
        for (int mi = 0; mi < 4; ++mi)
#pragma unroll
            for (int ni = 0; ni < 4; ++ni)
                acc[mi][ni] = __builtin_amdgcn_mfma_f32_16x16x32_bf16(
                    af[mi], bf[ni], acc[mi][ni], 0, 0, 0);
        __syncthreads();
    }

    unsigned short* ob = (unsigned short*)outp;
    float* of = (float*)outp;
#pragma unroll
    for (int ni = 0; ni < 4; ++ni) {
        const int col = n0 + wx * 64 + ni * 16 + l16;
        const float bcol = bias[col];
#pragma unroll
        for (int mi = 0; mi < 4; ++mi) {
#pragma unroll
            for (int r = 0; r < 4; ++r) {
                int row = m0 + wy * 64 + mi * 16 + quad * 4 + r;
                if (row < N_NODES) {
                    float v = acc[mi][ni][r] + bcol;
                    if (relu) v = fmaxf(v, 0.f);
                    if (out_bf16) ob[(size_t)row * D + col] = f2bf(v);
                    else          of[(size_t)row * D + col] = v;
                }
            }
        }
    }
}

// ---------------------------------------------------------------------------
extern "C" void kernel_launch(void* const* d_in, const int* in_sizes, int n_in,
                              void* d_out, int out_size, void* d_ws, size_t ws_size,
                              hipStream_t stream) {
    const float* x    = (const float*)d_in[0];
    const int*   ei   = (const int*)d_in[1];   // int32 on device!
    const float* W_l1 = (const float*)d_in[2];
    const float* b1   = (const float*)d_in[3];
    const float* W_r1 = (const float*)d_in[4];
    const float* W_l2 = (const float*)d_in[5];
    const float* b2   = (const float*)d_in[6];
    const float* W_r2 = (const float*)d_in[7];
    float* out = (float*)d_out;

    const int* src = ei;
    const int* tgt = ei + N_EDGES;

    char* w = (char*)d_ws;
    size_t o = 0;
    auto alloc = [&](size_t bytes) {
        size_t p = o;
        o = (o + bytes + 255) & ~(size_t)255;
        return p;
    };
    int*  bin_cnt  = (int*)(w + alloc((size_t)NBINS * CNT_STRIDE * 4));
    int*  bin_base = (int*)(w + alloc((size_t)(NBINS + 1) * 4));
    int*  ovf_cnt  = (int*)(w + alloc(256));
    unsigned int* bin_buf = (unsigned int*)(w + alloc((size_t)NBINS * CAPB * 4));
    int2* ovf      = (int2*)(w + alloc((size_t)OVF_MAX * 8));
    int*  offs     = (int*)(w + alloc((size_t)(N_NODES + 1) * 4));
    int*  sorted_src = (int*)(w + alloc((size_t)N_EDGES * 4));
    unsigned short* xb   = (unsigned short*)(w + alloc((size_t)N_NODES * D * 2));
    unsigned short* hb   = (unsigned short*)(w + alloc((size_t)N_NODES * D * 2));
    unsigned short* aggb = (unsigned short*)(w + alloc((size_t)N_NODES * D * 2));
    unsigned short* Bp1  = (unsigned short*)(w + alloc((size_t)512 * D * 2));
    unsigned short* Bp2  = (unsigned short*)(w + alloc((size_t)512 * D * 2));
    (void)ws_size; (void)in_sizes; (void)n_in; (void)out_size;

    hipMemsetAsync(bin_cnt, 0, (size_t)NBINS * CNT_STRIDE * 4, stream);
    hipMemsetAsync(ovf_cnt, 0, 4, stream);

    const int EB = (N_EDGES + 255) / 256;
    binfill_kernel<<<EB, 256, 0, stream>>>(src, tgt, bin_cnt, bin_buf, ovf, ovf_cnt);
    scan_bins<<<1, 256, 0, stream>>>(bin_cnt, bin_base, offs);
    bin_expand<<<NBINS, 256, 0, stream>>>(bin_cnt, bin_base, bin_buf, offs, sorted_src);

    // bf16 conversions / weight packing
    const int n8 = N_NODES * D / 8;            // 3.2M
    convert_kernel<<<(n8 + 255) / 256, 256, 0, stream>>>(x, xb, n8);
    pack_b_kernel<<<64, 256, 0, stream>>>(W_l1, W_r1, Bp1);
    pack_b_kernel<<<64, 256, 0, stream>>>(W_l2, W_r2, Bp2);

    const int AGG_B = (N_NODES + 3) / 4;
    dim3 ggrid(2, (N_NODES + 127) / 128);      // (2, 782)

    // Layer 1
    aggregate_bf16<<<AGG_B, 256, 0, stream>>>(xb, aggb, offs, sorted_src, ovf, ovf_cnt);
    gemm_mfma<<<ggrid, 256, 0, stream>>>(aggb, xb, Bp1, b1, hb, 1, 1);

    // Layer 2
    aggregate_bf16<<<AGG_B, 256, 0, stream>>>(hb, aggb, offs, sorted_src, ovf, ovf_cnt);
    gemm_mfma<<<ggrid, 256, 0, stream>>>(aggb, hb, Bp2, b2, out, 0, 0);
}

// Round 9
// 976.370 us; speedup vs baseline: 1.4408x; 1.0883x over previous
//
#include <hip/hip_runtime.h>
#include <hip/hip_bf16.h>
#include <cstdint>
#include <cstddef>

#define N_NODES 100000
#define N_EDGES 3200000
#define D 256
#define NBINS 1563          // ceil(100000/64), bin = tgt >> 6
#define NSUB 8              // sub-buffers per bin, one per XCD (blockIdx & 7)
#define SUBCAP 384          // per-(bin,xcd) capacity: mean 256, +8 sigma
#define CNT_STRIDE 16       // pad counters to 64 B (one line per counter)
#define OVF_MAX (1 << 20)   // overflow list capacity (guaranteed-correct fallback)

typedef __attribute__((ext_vector_type(8))) short short8;   // 8 bf16 = 4 VGPRs
typedef __attribute__((ext_vector_type(4))) float f32x4;

__device__ inline unsigned short f2bf(float f) {            // RNE fp32->bf16
    unsigned int u = __float_as_uint(f);
    u += 0x7FFFu + ((u >> 16) & 1u);
    return (unsigned short)(u >> 16);
}
__device__ inline float bf2f(unsigned short h) {
    return __uint_as_float(((unsigned int)h) << 16);
}

// ---------------------------------------------------------------------------
// Pass 1: XCD-private bin-append. Sub-buffer = blockIdx&7 (round-robin
// workgroup->XCD mapping) so each 64B line of bin_buf is written by ONE XCD;
// per-XCD active set = NBINS*SUBCAP*4 = 2.4 MB < 4 MB L2 -> lines stay
// resident and are evicted once (kills the ~10x cross-XCD line thrash that
// held all scatter variants at ~700 GB/s of HBM writes).
// Entry packs (t_local<<17 | s) into 4 B (s < 2^17).
// ---------------------------------------------------------------------------
__global__ void binfill_kernel(const int* __restrict__ src,
                               const int* __restrict__ tgt,
                               int* __restrict__ bin_cnt,
                               unsigned int* __restrict__ bin_buf,
                               int2* __restrict__ ovf,
                               int* __restrict__ ovf_cnt) {
    int e = blockIdx.x * blockDim.x + threadIdx.x;
    if (e >= N_EDGES) return;
    const int xs = blockIdx.x & (NSUB - 1);
    int t = tgt[e];
    int s = src[e];
    if (t >= 0 && t < N_NODES && s >= 0 && s < N_NODES) {
        int b = t >> 6;
        int p = atomicAdd(&bin_cnt[(b * NSUB + xs) * CNT_STRIDE], 1);
        if (p < SUBCAP) {
            bin_buf[((size_t)b * NSUB + xs) * SUBCAP + p] =
                ((unsigned int)(t & 63) << 17) | (unsigned int)s;
        } else {
            int q = atomicAdd(ovf_cnt, 1);
            if (q < OVF_MAX) ovf[q] = make_int2(t, s);
        }
    }
}

// ---------------------------------------------------------------------------
// Exclusive scan over per-bin totals (sum of 8 clamped sub-counts) -> bin_base.
// Single block, 7 chunks of 256. Also writes offs[N_NODES] = total.
// ---------------------------------------------------------------------------
__global__ __launch_bounds__(256) void scan_bins(const int* __restrict__ bin_cnt,
                                                 int* __restrict__ bin_base,
                                                 int* __restrict__ offs) {
    __shared__ int s[256];
    __shared__ int carry;
    const int t = threadIdx.x;
    if (t == 0) carry = 0;
    __syncthreads();
    for (int chunk = 0; chunk < (NBINS + 255) / 256; ++chunk) {
        int b = chunk * 256 + t;
        int v = 0;
        if (b < NBINS) {
#pragma unroll
            for (int x = 0; x < NSUB; ++x) {
                int c = bin_cnt[(b * NSUB + x) * CNT_STRIDE];
                v += (c > SUBCAP) ? SUBCAP : c;
            }
        }
        s[t] = v;
        __syncthreads();
        for (int d = 1; d < 256; d <<= 1) {
            int x = (t >= d) ? s[t - d] : 0;
            __syncthreads();
            s[t] += x;
            __syncthreads();
        }
        if (b < NBINS) bin_base[b] = carry + s[t] - v;   // exclusive
        __syncthreads();
        if (t == 0) carry += s[255];
        __syncthreads();
    }
    if (t == 0) {
        bin_base[NBINS] = carry;
        offs[N_NODES] = carry;
    }
}

// ---------------------------------------------------------------------------
// Pass 2: per-bin expansion into a dense exact CSR. One block per bin.
// Compacts the 8 sub-lists into LDS; per-node counts/offsets via LDS atomics
// (no global atomics); coalesced reads, bin-local CSR writes.
// ---------------------------------------------------------------------------
__global__ __launch_bounds__(256) void bin_expand(const int* __restrict__ bin_cnt,
                                                  const int* __restrict__ bin_base,
                                                  const unsigned int* __restrict__ bin_buf,
                                                  int* __restrict__ offs,
                                                  int* __restrict__ sorted_src) {
    __shared__ unsigned int ent[NSUB * SUBCAP];
    __shared__ int cnt64[64], off64[64], cur64[64];
    __shared__ int nsub[NSUB], presub[NSUB + 1];
    const int b = blockIdx.x;
    const int tid = threadIdx.x;
    const int base = bin_base[b];

    if (tid < NSUB) {
        int c = bin_cnt[(b * NSUB + tid) * CNT_STRIDE];
        nsub[tid] = (c > SUBCAP) ? SUBCAP : c;
    }
    if (tid < 64) cnt64[tid] = 0;
    __syncthreads();
    if (tid == 0) {
        int run = 0;
#pragma unroll
        for (int x = 0; x < NSUB; ++x) { presub[x] = run; run += nsub[x]; }
        presub[NSUB] = run;
    }
    __syncthreads();
    const int n = presub[NSUB];

    for (int idx = tid; idx < NSUB * SUBCAP; idx += 256) {
        int x = idx / SUBCAP, i = idx - x * SUBCAP;
        if (i < nsub[x]) {
            unsigned int v = bin_buf[((size_t)b * NSUB + x) * SUBCAP + i];
            ent[presub[x] + i] = v;
            atomicAdd(&cnt64[v >> 17], 1);
        }
    }
    __syncthreads();
    if (tid == 0) {
        int run = 0;
#pragma unroll
        for (int i = 0; i < 64; ++i) { off64[i] = run; run += cnt64[i]; }
    }
    __syncthreads();
    if (tid < 64) {
        cur64[tid] = off64[tid];
        int node = b * 64 + tid;
        if (node < N_NODES) offs[node] = base + off64[tid];
    }
    __syncthreads();
    for (int i = tid; i < n; i += 256) {
        unsigned int v = ent[i];
        int p = atomicAdd(&cur64[v >> 17], 1);
        sorted_src[base + p] = (int)(v & 0x1FFFFu);
    }
}

// ---------------------------------------------------------------------------
// fp32 -> bf16 bulk convert (8 elements / thread)
// ---------------------------------------------------------------------------
__global__ __launch_bounds__(256) void convert_kernel(const float* __restrict__ in,
                                                      unsigned short* __restrict__ out,
                                                      int n8) {
    int i = blockIdx.x * 256 + threadIdx.x;
    if (i >= n8) return;
    const float4 a = ((const float4*)in)[i * 2 + 0];
    const float4 b = ((const float4*)in)[i * 2 + 1];
    short8 v;
    v[0] = (short)f2bf(a.x); v[1] = (short)f2bf(a.y);
    v[2] = (short)f2bf(a.z); v[3] = (short)f2bf(a.w);
    v[4] = (short)f2bf(b.x); v[5] = (short)f2bf(b.y);
    v[6] = (short)f2bf(b.z); v[7] = (short)f2bf(b.w);
    ((short8*)out)[i] = v;
}

// ---------------------------------------------------------------------------
// Pack B=[Wl;Wr] (512x256 fp32 row-major) into MFMA B-fragment order, bf16.
// ---------------------------------------------------------------------------
__global__ __launch_bounds__(256) void pack_b_kernel(const float* __restrict__ Wl,
                                                     const float* __restrict__ Wr,
                                                     unsigned short* __restrict__ Bp) {
    int t = blockIdx.x * 256 + threadIdx.x;   // 16*16*64 = 16384
    if (t >= 16384) return;
    int lane = t & 63, kb = (t >> 6) & 15, ntile = t >> 10;
    int n = ntile * 16 + (lane & 15);
    int kbase = kb * 32 + (lane >> 4) * 8;
    short8 v;
#pragma unroll
    for (int j = 0; j < 8; ++j) {
        int k = kbase + j;
        const float* W = (k < 256) ? Wl : Wr;
        v[j] = (short)f2bf(W[(size_t)(k & 255) * D + n]);
    }
    ((short8*)Bp)[t] = v;
}

// ---------------------------------------------------------------------------
// Mean aggregation over bf16 rows (one wave per node, CSR):
//   half-wave per edge, 16 B short8 per lane; 8 edges/iter (4 gathers in
//   flight); next iteration's indices pipelined. Overflow list (normally
//   empty) scanned only when non-empty; mean divisor uses the exact degree.
// ---------------------------------------------------------------------------
__device__ inline void acc8(float& a0, float& a1, float& a2, float& a3,
                            float& a4, float& a5, float& a6, float& a7,
                            const short8& r) {
    a0 += bf2f((unsigned short)r[0]); a1 += bf2f((unsigned short)r[1]);
    a2 += bf2f((unsigned short)r[2]); a3 += bf2f((unsigned short)r[3]);
    a4 += bf2f((unsigned short)r[4]); a5 += bf2f((unsigned short)r[5]);
    a6 += bf2f((unsigned short)r[6]); a7 += bf2f((unsigned short)r[7]);
}

__global__ __launch_bounds__(256) void aggregate_bf16(
    const unsigned short* __restrict__ in, unsigned short* __restrict__ out,
    const int* __restrict__ offs, const int* __restrict__ sorted_src,
    const int2* __restrict__ ovf, const int* __restrict__ ovf_cnt) {
    int node = blockIdx.x * 4 + (threadIdx.x >> 6);
    if (node >= N_NODES) return;
    const int lane = threadIdx.x & 63;
    const int half = lane >> 5;                 // 0 or 1: which edge of a pair
    const int l32  = lane & 31;                 // 32 lanes x 8 bf16 = 256 cols
    const int beg = offs[node];
    const int inb = offs[node + 1] - beg;
    const unsigned short* __restrict__ rowp = in + (size_t)l32 * 8;

    float a0 = 0.f, a1 = 0.f, a2 = 0.f, a3 = 0.f;
    float a4 = 0.f, a5 = 0.f, a6 = 0.f, a7 = 0.f;

    // indices for iteration 0: edges (2*p + half), p = 0..3
    int i0 = (0 + half < inb) ? sorted_src[beg + 0 + half] : -1;
    int i1 = (2 + half < inb) ? sorted_src[beg + 2 + half] : -1;
    int i2 = (4 + half < inb) ? sorted_src[beg + 4 + half] : -1;
    int i3 = (6 + half < inb) ? sorted_src[beg + 6 + half] : -1;

    for (int k = 0; k < inb; k += 8) {
        // prefetch next iteration's indices (off the gather critical path)
        const int kn = k + 8;
        int n0 = (kn + 0 + half < inb) ? sorted_src[beg + kn + 0 + half] : -1;
        int n1 = (kn + 2 + half < inb) ? sorted_src[beg + kn + 2 + half] : -1;
        int n2 = (kn + 4 + half < inb) ? sorted_src[beg + kn + 4 + half] : -1;
        int n3 = (kn + 6 + half < inb) ? sorted_src[beg + kn + 6 + half] : -1;

        // 4 independent 16 B gathers per lane
        short8 r0 = {}, r1 = {}, r2 = {}, r3 = {};
        if (i0 >= 0) r0 = *(const short8*)(rowp + (size_t)i0 * D);
        if (i1 >= 0) r1 = *(const short8*)(rowp + (size_t)i1 * D);
        if (i2 >= 0) r2 = *(const short8*)(rowp + (size_t)i2 * D);
        if (i3 >= 0) r3 = *(const short8*)(rowp + (size_t)i3 * D);

        acc8(a0, a1, a2, a3, a4, a5, a6, a7, r0);
        acc8(a0, a1, a2, a3, a4, a5, a6, a7, r1);
        acc8(a0, a1, a2, a3, a4, a5, a6, a7, r2);
        acc8(a0, a1, a2, a3, a4, a5, a6, a7, r3);

        i0 = n0; i1 = n1; i2 = n2; i3 = n3;
    }

    // rare path: some sub-bin overflowed -> scan the (tiny) overflow list
    int extra = 0;
    int m = *ovf_cnt;
    if (m > 0) {
        if (m > OVF_MAX) m = OVF_MAX;
        for (int q = half; q < m; q += 2) {
            int2 ts = ovf[q];
            if (ts.x == node) {
                short8 r = *(const short8*)(rowp + (size_t)ts.y * D);
                acc8(a0, a1, a2, a3, a4, a5, a6, a7, r);
                ++extra;
            }
        }
    }

    // combine the two half-wave partial sums (once per node)
    a0 += __shfl_xor(a0, 32); a1 += __shfl_xor(a1, 32);
    a2 += __shfl_xor(a2, 32); a3 += __shfl_xor(a3, 32);
    a4 += __shfl_xor(a4, 32); a5 += __shfl_xor(a5, 32);
    a6 += __shfl_xor(a6, 32); a7 += __shfl_xor(a7, 32);
    extra += __shfl_xor(extra, 32);

    if (half == 0) {
        const float inv = 1.0f / fmaxf((float)(inb + extra), 1.0f);
        short8 v;
        v[0] = (short)f2bf(a0 * inv); v[1] = (short)f2bf(a1 * inv);
        v[2] = (short)f2bf(a2 * inv); v[3] = (short)f2bf(a3 * inv);
        v[4] = (short)f2bf(a4 * inv); v[5] = (short)f2bf(a5 * inv);
        v[6] = (short)f2bf(a6 * inv); v[7] = (short)f2bf(a7 * inv);
        *(short8*)(out + (size_t)node * D + l32 * 8) = v;
    }
}

// ---------------------------------------------------------------------------
// MFMA GEMM: out = [A0 | A1] @ Bp + bias, K=512, optional ReLU, bf16/fp32 out.
// ---------------------------------------------------------------------------
__global__ __launch_bounds__(256) void gemm_mfma(
    const unsigned short* __restrict__ A0, const unsigned short* __restrict__ A1,
    const unsigned short* __restrict__ Bp, const float* __restrict__ bias,
    void* __restrict__ outp, int relu, int out_bf16) {
    __shared__ unsigned short As[128][40];   // +8 pad: 80 B row stride
    const int m0 = blockIdx.y * 128;
    const int n0 = blockIdx.x * 128;
    const int t = threadIdx.x;
    const int wave = t >> 6, lane = t & 63;
    const int wy = wave >> 1, wx = wave & 1;
    const int quad = lane >> 4, l16 = lane & 15;

    const int arow = t >> 1;            // 0..127
    const int ahalf = (t & 1) * 16;     // 0 / 16 (bf16 elems)

    f32x4 acc[4][4] = {};

    for (int kb = 0; kb < 16; ++kb) {
        const int k0 = kb * 32;
        const unsigned short* A = (k0 < 256) ? A0 : A1;
        const int kk = k0 & 255;

        short8 v0 = {}, v1 = {};
        if (m0 + arow < N_NODES) {
            const unsigned short* p = A + (size_t)(m0 + arow) * D + kk + ahalf;
            v0 = *(const short8*)p;
            v1 = *(const short8*)(p + 8);
        }
        *(short8*)&As[arow][ahalf + 0] = v0;
        *(short8*)&As[arow][ahalf + 8] = v1;
        __syncthreads();

        short8 af[4], bf[4];
#pragma unroll
        for (int mi = 0; mi < 4; ++mi)
            af[mi] = *(const short8*)&As[wy * 64 + mi * 16 + l16][quad * 8];
#pragma unroll
        for (int ni = 0; ni < 4; ++ni) {
            int ntile = (n0 >> 4) + wx * 4 + ni;
            bf[ni] = ((const short8*)Bp)[(size_t)(ntile * 16 + kb) * 64 + lane];
        }
#pragma unroll
        for (int mi = 0; mi < 4; ++mi)
#pragma unroll
            for (int ni = 0; ni < 4; ++ni)
                acc[mi][ni] = __builtin_amdgcn_mfma_f32_16x16x32_bf16(
                    af[mi], bf[ni], acc[mi][ni], 0, 0, 0);
        __syncthreads();
    }

    unsigned short* ob = (unsigned short*)outp;
    float* of = (float*)outp;
#pragma unroll
    for (int ni = 0; ni < 4; ++ni) {
        const int col = n0 + wx * 64 + ni * 16 + l16;
        const float bcol = bias[col];
#pragma unroll
        for (int mi = 0; mi < 4; ++mi) {
#pragma unroll
            for (int r = 0; r < 4; ++r) {
                int row = m0 + wy * 64 + mi * 16 + quad * 4 + r;
                if (row < N_NODES) {
                    float v = acc[mi][ni][r] + bcol;
                    if (relu) v = fmaxf(v, 0.f);
                    if (out_bf16) ob[(size_t)row * D + col] = f2bf(v);
                    else          of[(size_t)row * D + col] = v;
                }
            }
        }
    }
}

// ---------------------------------------------------------------------------
extern "C" void kernel_launch(void* const* d_in, const int* in_sizes, int n_in,
                              void* d_out, int out_size, void* d_ws, size_t ws_size,
                              hipStream_t stream) {
    const float* x    = (const float*)d_in[0];
    const int*   ei   = (const int*)d_in[1];   // int32 on device!
    const float* W_l1 = (const float*)d_in[2];
    const float* b1   = (const float*)d_in[3];
    const float* W_r1 = (const float*)d_in[4];
    const float* W_l2 = (const float*)d_in[5];
    const float* b2   = (const float*)d_in[6];
    const float* W_r2 = (const float*)d_in[7];
    float* out = (float*)d_out;

    const int* src = ei;
    const int* tgt = ei + N_EDGES;

    char* w = (char*)d_ws;
    size_t o = 0;
    auto alloc = [&](size_t bytes) {
        size_t p = o;
        o = (o + bytes + 255) & ~(size_t)255;
        return p;
    };
    int*  bin_cnt  = (int*)(w + alloc((size_t)NBINS * NSUB * CNT_STRIDE * 4));
    int*  bin_base = (int*)(w + alloc((size_t)(NBINS + 1) * 4));
    int*  ovf_cnt  = (int*)(w + alloc(256));
    unsigned int* bin_buf = (unsigned int*)(w + alloc((size_t)NBINS * NSUB * SUBCAP * 4));
    int2* ovf      = (int2*)(w + alloc((size_t)OVF_MAX * 8));
    int*  offs     = (int*)(w + alloc((size_t)(N_NODES + 1) * 4));
    int*  sorted_src = (int*)(w + alloc((size_t)N_EDGES * 4));
    unsigned short* xb   = (unsigned short*)(w + alloc((size_t)N_NODES * D * 2));
    unsigned short* hb   = (unsigned short*)(w + alloc((size_t)N_NODES * D * 2));
    unsigned short* aggb = (unsigned short*)(w + alloc((size_t)N_NODES * D * 2));
    unsigned short* Bp1  = (unsigned short*)(w + alloc((size_t)512 * D * 2));
    unsigned short* Bp2  = (unsigned short*)(w + alloc((size_t)512 * D * 2));
    (void)ws_size; (void)in_sizes; (void)n_in; (void)out_size;

    hipMemsetAsync(bin_cnt, 0, (size_t)NBINS * NSUB * CNT_STRIDE * 4, stream);
    hipMemsetAsync(ovf_cnt, 0, 4, stream);

    const int EB = (N_EDGES + 255) / 256;
    binfill_kernel<<<EB, 256, 0, stream>>>(src, tgt, bin_cnt, bin_buf, ovf, ovf_cnt);
    scan_bins<<<1, 256, 0, stream>>>(bin_cnt, bin_base, offs);
    bin_expand<<<NBINS, 256, 0, stream>>>(bin_cnt, bin_base, bin_buf, offs, sorted_src);

    // bf16 conversions / weight packing
    const int n8 = N_NODES * D / 8;            // 3.2M
    convert_kernel<<<(n8 + 255) / 256, 256, 0, stream>>>(x, xb, n8);
    pack_b_kernel<<<64, 256, 0, stream>>>(W_l1, W_r1, Bp1);
    pack_b_kernel<<<64, 256, 0, stream>>>(W_l2, W_r2, Bp2);

    const int AGG_B = (N_NODES + 3) / 4;
    dim3 ggrid(2, (N_NODES + 127) / 128);      // (2, 782)

    // Layer 1
    aggregate_bf16<<<AGG_B, 256, 0, stream>>>(xb, aggb, offs, sorted_src, ovf, ovf_cnt);
    gemm_mfma<<<ggrid, 256, 0, stream>>>(aggb, xb, Bp1, b1, hb, 1, 1);

    // Layer 2
    aggregate_bf16<<<AGG_B, 256, 0, stream>>>(hb, aggb, offs, sorted_src, ovf, ovf_cnt);
    gemm_mfma<<<ggrid, 256, 0, stream>>>(aggb, hb, Bp2, b2, out, 0, 0);
}